// Round 11
// baseline (122.213 us; speedup 1.0000x reference)
//
#include <hip/hip_runtime.h>

typedef short s16x8 __attribute__((ext_vector_type(8)));
typedef float f32x4 __attribute__((ext_vector_type(4)));
typedef float f32x16 __attribute__((ext_vector_type(16)));
typedef unsigned int u32;
typedef u32 u32x2 __attribute__((ext_vector_type(2)));
typedef u32 u32x4 __attribute__((ext_vector_type(4)));
typedef unsigned short u16;

#define MFMA16(a, b, c) __builtin_amdgcn_mfma_f32_16x16x32_bf16((a), (b), (c), 0, 0, 0)
#define MFMA32(a, b, c) __builtin_amdgcn_mfma_f32_32x32x16_bf16((a), (b), (c), 0, 0, 0)

__device__ __forceinline__ u16 f2bf(float f) {
  unsigned u = __builtin_bit_cast(unsigned, f);
  unsigned r = (u + 0x7FFFu + ((u >> 16) & 1u)) >> 16;
  return (u16)r;
}

__device__ __forceinline__ u32 pack2bf(float lo, float hi) {
  return (u32)f2bf(lo) | ((u32)f2bf(hi) << 16);
}

__device__ __forceinline__ u32 cvtpk(float lo, float hi) {
  u32 r;
  asm("v_cvt_pk_bf16_f32 %0, %1, %2" : "=v"(r) : "v"(lo), "v"(hi));
  return r;
}

__device__ __forceinline__ float bf2f(u32 lo16) {
  return __builtin_bit_cast(float, lo16 << 16);
}

// async global->LDS, 16B per lane. LDS dest must be wave-uniform base (HW adds lane*16).
__device__ __forceinline__ void gl_lds16(const u16* g, u16* s) {
  __builtin_amdgcn_global_load_lds(
      (const __attribute__((address_space(1))) void*)g,
      (__attribute__((address_space(3))) void*)s, 16, 0, 0);
}

// ---------------- fp32 -> bf16 elementwise (x) ----------------
__global__ __launch_bounds__(256) void cvt_bf16(const float* __restrict__ in,
                                                u16* __restrict__ out, int n4) {
  int i = blockIdx.x * 256 + threadIdx.x;
  if (i < n4) {
    float4 v = reinterpret_cast<const float4*>(in)[i];
    ushort4 o;
    o.x = f2bf(v.x); o.y = f2bf(v.y); o.z = f2bf(v.z); o.w = f2bf(v.w);
    reinterpret_cast<ushort4*>(out)[i] = o;
  }
}

// ---------------- all 4 weights: fp32 [1024][1024] -> bf16 transpose (one kernel) ----
__global__ __launch_bounds__(256) void transp4(const float* __restrict__ wq,
                                               const float* __restrict__ wk,
                                               const float* __restrict__ wv,
                                               const float* __restrict__ wo,
                                               u16* __restrict__ wqkvt,
                                               u16* __restrict__ wot, float qscale) {
  __shared__ float tile[64][65];
  int z = blockIdx.z;
  const float* W = (z == 0) ? wq : (z == 1) ? wk : (z == 2) ? wv : wo;
  u16* out = (z < 3) ? (wqkvt + z * 1048576) : wot;
  float sc = (z == 0) ? qscale : 1.0f;
  int n0 = blockIdx.x * 64, k0 = blockIdx.y * 64;
  int t = threadIdx.x;
#pragma unroll
  for (int i = 0; i < 16; i++) {
    int idx = t + i * 256;
    int r = idx >> 6, c = idx & 63;
    tile[r][c] = W[(k0 + r) * 1024 + (n0 + c)];
  }
  __syncthreads();
#pragma unroll
  for (int i = 0; i < 16; i++) {
    int idx = t + i * 256;
    int r = idx >> 6, c = idx & 63;
    out[(n0 + r) * 1024 + (k0 + c)] = f2bf(tile[c][r] * sc);
  }
}

// ---------------- 2-phase global_load_lds GEMM: C = A[M][1024] @ Bt[N][1024]^T ------
// MODE 0: fused QKV epilogue. outp = base of {qb, kb, vtb} (each 4M u16).
//         V^T keys are stored bit2<->bit3 swapped within each 16-block so that
//         attention's P fragments need no cross-lane exchange.
// MODE 1: fp32 out [M][1024] = acc + bias[n]
template <int MODE>
__global__ __launch_bounds__(256) void gemm2(const u16* __restrict__ A,
                                             const u16* __restrict__ Bt,
                                             const float* __restrict__ bias,
                                             void* __restrict__ outp) {
  constexpr int K = 1024, NT = K / 32;
  __shared__ __align__(16) u16 As[2][128 * 32];
  __shared__ __align__(16) u16 Bs[2][128 * 32];
  int t = threadIdx.x, w = t >> 6, l = t & 63;
  int m0 = blockIdx.y * 128, n0 = blockIdx.x * 128;
  int wm = (w >> 1) * 64, wn = (w & 1) * 64;
  int g = l >> 4, ql = l & 15;

  f32x4 acc[4][4];
#pragma unroll
  for (int i = 0; i < 4; i++)
#pragma unroll
    for (int j = 0; j < 4; j++) acc[i][j] = f32x4{0.f, 0.f, 0.f, 0.f};

  int lrow = l >> 2, lcol = (l & 3) * 8;
  const u16* Ag0 = A + (m0 + 32 * w + lrow) * K + lcol;
  const u16* Bg0 = Bt + (n0 + 32 * w + lrow) * K + lcol;
  u16* Asw[2] = {&As[0][(32 * w) * 32], &As[1][(32 * w) * 32]};
  u16* Bsw[2] = {&Bs[0][(32 * w) * 32], &Bs[1][(32 * w) * 32]};

#define STAGE(buf, kt)                              \
  do {                                              \
    int k0_ = (kt) * 32;                            \
    gl_lds16(Ag0 + k0_, Asw[buf]);                  \
    gl_lds16(Ag0 + 16 * K + k0_, Asw[buf] + 512);   \
    gl_lds16(Bg0 + k0_, Bsw[buf]);                  \
    gl_lds16(Bg0 + 16 * K + k0_, Bsw[buf] + 512);   \
  } while (0)

#define COMPUTE(buf)                                                              \
  do {                                                                            \
    s16x8 af[4], bv[4];                                                           \
    _Pragma("unroll") for (int fm = 0; fm < 4; fm++)                              \
        af[fm] = *reinterpret_cast<const s16x8*>(                                 \
            &As[buf][(wm + fm * 16 + ql) * 32 + g * 8]);                          \
    _Pragma("unroll") for (int fn = 0; fn < 4; fn++)                              \
        bv[fn] = *reinterpret_cast<const s16x8*>(                                 \
            &Bs[buf][(wn + fn * 16 + ql) * 32 + g * 8]);                          \
    _Pragma("unroll") for (int fm = 0; fm < 4; fm++)                              \
        _Pragma("unroll") for (int fn = 0; fn < 4; fn++)                          \
            acc[fm][fn] = MFMA16(af[fm], bv[fn], acc[fm][fn]);                    \
  } while (0)

  STAGE(0, 0);
  __syncthreads();
  int cur = 0;
  for (int kt = 0; kt < NT - 1; kt++) {
    STAGE(cur ^ 1, kt + 1);
    COMPUTE(cur);
    __syncthreads();
    cur ^= 1;
  }
  COMPUTE(cur);
#undef STAGE
#undef COMPUTE

#pragma unroll
  for (int fm = 0; fm < 4; fm++)
#pragma unroll
    for (int fn = 0; fn < 4; fn++)
#pragma unroll
      for (int j = 0; j < 4; j++) {
        int m = m0 + wm + fm * 16 + g * 4 + j;
        int n = n0 + wn + fn * 16 + ql;
        float v = acc[fm][fn][j];
        if (MODE == 0) {
          int proj = n >> 10, nn = n & 1023;
          int bh = (m >> 11) * 16 + (nn >> 6);
          int hd = nn & 63, srow = m & 2047;
          u16* o = (u16*)outp + proj * 4194304;
          if (proj < 2) {
            o[(bh * 2048 + srow) * 64 + hd] = f2bf(v);
          } else {
            // key-permuted V^T: swap bits 2<->3 of key index within 16-block
            int sp = (srow & ~12) | ((srow & 4) << 1) | ((srow & 8) >> 1);
            o[(bh * 64 + hd) * 2048 + sp] = f2bf(v);
          }
        } else {
          ((float*)outp)[m * 1024 + n] = v + bias[n];
        }
      }
}

// ---------------- flash attention: 8-wave blocks, shared K/V in LDS ----------------
// 3-buffer double-depth pipeline, counted vmcnt (T3/T4): iter i computes buf i%3,
// stages pair i+2 into buf (i+2)%3 (freed at i-1), waits vmcnt(2) (pair i+1 landed,
// pair i+2 in flight), ONE raw s_barrier per 64-key iteration. No vmcnt(0) in loop.
// Q,K: [BH=32][S=2048][64] bf16 (Q pre-scaled by 0.125*log2e); Vt: [BH][64][2048] bf16
// (key-permuted). 512 blocks x 512 threads. Wave w: q rows qc*256+w*32..+32.
// Waves 0-3 stage K (2 gl_lds16/iter), waves 4-7 stage V (2 gl_lds16/iter).
__global__ __launch_bounds__(512, 4) void attn_kernel(const u16* __restrict__ Q,
                                                      const u16* __restrict__ Kb,
                                                      const u16* __restrict__ Vt,
                                                      u16* __restrict__ Ctx,
                                                      u16* __restrict__ part_o,
                                                      float* __restrict__ part_l) {
  // 3 bufs x (K 4096 u16 + V 4096 u16) = 24576 u16 = 48 KB; tl overlays after loop.
  __shared__ __align__(16) u16 shm[24576];
  int tid = threadIdx.x, w = tid >> 6, l = tid & 63;
  int lq = l & 31, h = l >> 5;

  int B = blockIdx.x;
  int head = (B & 7) + 8 * ((B >> 3) & 3);  // head % 8 == B % 8 -> XCD-pinned
  int u = B >> 5;                           // unit 0..15, longest first
  // chunking in 64-key PAIRS: qc0:[4]D qc1:[8]D qc2:[12]D qc3:[16]D
  // qc4:[10,10] qc5:[8,8,8] qc6:[10,9,9] qc7:[8,8,8,8]  (partial bases as R10)
  const signed char QCp[16]  = {3, 2, 4, 4, 6, 6, 6, 5, 5, 5, 7, 7, 7, 7, 1, 0};
  const signed char T0pv[16] = {0, 0, 0, 10, 0, 10, 19, 0, 8, 16, 0, 8, 16, 24, 0, 0};
  const signed char LENv[16] = {16, 12, 10, 10, 10, 9, 9, 8, 8, 8, 8, 8, 8, 8, 8, 4};
  const signed char CKv[16]  = {0, 0, 0, 1, 0, 1, 2, 0, 1, 2, 0, 1, 2, 3, 0, 0};
  int qc = QCp[u], ck = CKv[u], t0p = T0pv[u], n = LENv[u];
  int dtile = qc * 8 + w;       // wave's diagonal tile (32-key units)
  int q0w = qc * 256 + w * 32;  // wave's q base
  int q = q0w + lq;

  const u16* Qp = Q + (head * 2048 + q0w) * 64;
  const u16* Kp = Kb + head * 2048 * 64;
  const u16* Vp = Vt + head * 64 * 2048;

  // Q fragments (B-operand: Q^T[d][q], lane holds q=lq, d = f*16 + h*8 + j)
  s16x8 qf[4];
#pragma unroll
  for (int f = 0; f < 4; f++)
    qf[f] = *reinterpret_cast<const s16x8*>(Qp + lq * 64 + f * 16 + h * 8);

  // staging sources (pre-swizzled global addr, rule #21) + LDS offsets
  const u16 *gs0, *gs1;
  int gstride, lo0, lo1;
  if (w < 4) {
    // K: per pair 64 rows x 128B; wave w rows [w*16, w*16+16), 8 rows per call
    int rowa = w * 16 + (l >> 3);
    gs0 = Kp + rowa * 64 + ((l & 7) ^ (rowa & 7)) * 8;
    gs1 = gs0 + 512;  // rows +8 (same XOR phase)
    gstride = 4096;   // 64 rows * 64 u16 per pair
    lo0 = w * 1024;
    lo1 = lo0 + 512;
  } else {
    // V^T packed per 32-key subtile: 32 LDS rows of 128B; call0 sub0, call1 sub1
    int lin = (w - 4) * 64 + l;
    int rp = lin >> 3, pos = lin & 7;
    int d = rp * 2 + (pos >> 2);
    int c = (pos & 3) ^ (rp & 3);
    gs0 = Vp + d * 2048 + c * 8;
    gs1 = gs0 + 32;  // subtile 1 (+32 keys)
    gstride = 64;    // +64 keys per pair
    lo0 = 4096 + (w - 4) * 512;
    lo1 = lo0 + 2048;
  }

#define STAGEP(buf, pi)                          \
  do {                                           \
    u16* sb_ = shm + (buf)*8192;                 \
    gl_lds16(gs0 + (pi)*gstride, sb_ + lo0);     \
    gl_lds16(gs1 + (pi)*gstride, sb_ + lo1);     \
  } while (0)

  f32x16 oacc[2];
#pragma unroll
  for (int dt = 0; dt < 2; dt++)
#pragma unroll
    for (int rr = 0; rr < 16; rr++) oacc[dt][rr] = 0.f;
  float lsum = 0.f;

  // prologue: stage pairs t0p, t0p+1 (n >= 4 always)
  STAGEP(0, t0p);
  STAGEP(1, t0p + 1);
  asm volatile("s_waitcnt vmcnt(2)" ::: "memory");
  __builtin_amdgcn_sched_barrier(0);
  __builtin_amdgcn_s_barrier();
  __builtin_amdgcn_sched_barrier(0);

  int cur = 0;
  for (int i = 0; i < n; i++) {
    u16* sbase = shm + cur * 8192;
    int tile0 = (t0p + i) * 2;

#pragma unroll
    for (int sub = 0; sub < 2; sub++) {
      int kt = tile0 + sub;
      if (kt <= dtile) {
        // K fragments from LDS (A-operand: K[key][d])
        s16x8 kc[4];
#pragma unroll
        for (int f = 0; f < 4; f++)
          kc[f] = *reinterpret_cast<const s16x8*>(
              &sbase[(sub * 32 + lq) * 64 + (((f * 2 + h) ^ (lq & 7)) * 8)]);

        f32x16 s;
#pragma unroll
        for (int rr = 0; rr < 16; rr++) s[rr] = 0.f;
        __builtin_amdgcn_s_setprio(1);
#pragma unroll
        for (int f = 0; f < 4; f++) s = MFMA32(kc[f], qf[f], s);
        __builtin_amdgcn_s_setprio(0);

        // softmax terms, fixed shift (no max); mask only on the diagonal tile
        float p[16];
        if (kt == dtile) {
          int kb = kt * 32;
#pragma unroll
          for (int rr = 0; rr < 16; rr++) {
            int key = kb + (rr & 3) + 8 * (rr >> 2) + 4 * h;
            float e = exp2f(s[rr]);
            p[rr] = (key <= q) ? e : 0.f;
          }
        } else {
#pragma unroll
          for (int rr = 0; rr < 16; rr++) p[rr] = exp2f(s[rr]);
        }
#pragma unroll
        for (int rr = 0; rr < 16; rr++) lsum += p[rr];

        // pack own regs directly into B-fragments (key order baked into V layout)
        u32 pw[2][4];
#pragma unroll
        for (int kh = 0; kh < 2; kh++)
#pragma unroll
          for (int uu = 0; uu < 4; uu++)
            pw[kh][uu] = cvtpk(p[kh * 8 + 2 * uu], p[kh * 8 + 2 * uu + 1]);

        // V fragments from LDS (A-operand: V^T[d][pos])
        const u16* vb = sbase + 4096 + sub * 2048;
        s16x8 vf[2][2];
#pragma unroll
        for (int dt = 0; dt < 2; dt++)
#pragma unroll
          for (int kh = 0; kh < 2; kh++) {
            int rp = dt * 16 + (lq >> 1);
            vf[dt][kh] = *reinterpret_cast<const s16x8*>(
                &vb[rp * 64 + (lq & 1) * 32 + (((kh * 2 + h) ^ (rp & 3)) * 8)]);
          }

        __builtin_amdgcn_s_setprio(1);
#pragma unroll
        for (int kh = 0; kh < 2; kh++) {
          s16x8 pf = __builtin_bit_cast(
              s16x8, u32x4{pw[kh][0], pw[kh][1], pw[kh][2], pw[kh][3]});
          oacc[0] = MFMA32(vf[0][kh], pf, oacc[0]);
          oacc[1] = MFMA32(vf[1][kh], pf, oacc[1]);
        }
        __builtin_amdgcn_s_setprio(0);
      }
    }

    // pipeline: stage pair i+2 into the buffer freed at iter i-1
    if (i + 2 < n) {
      int nb = cur + 2;
      if (nb >= 3) nb -= 3;
      STAGEP(nb, t0p + i + 2);
      asm volatile("s_waitcnt vmcnt(2)" ::: "memory");  // pair i+1 landed
    } else {
      asm volatile("s_waitcnt vmcnt(0)" ::: "memory");  // tail drain
    }
    __builtin_amdgcn_sched_barrier(0);
    __builtin_amdgcn_s_barrier();
    __builtin_amdgcn_sched_barrier(0);
    cur = (cur == 2) ? 0 : cur + 1;
  }
#undef STAGEP

  if (qc >= 4) {
    // partial record: rec = head*12 + base(qc) + ck  (layout identical to R10)
    int base = (qc == 4) ? 0 : (qc == 5) ? 2 : (qc == 6) ? 5 : 8;
    int rec = head * 12 + base + ck;
    u32* po = reinterpret_cast<u32*>(part_o) + (size_t)rec * 8192 + w * 1024 + l * 16;
#pragma unroll
    for (int dt = 0; dt < 2; dt++)
#pragma unroll
      for (int i = 0; i < 8; i++)
        po[dt * 8 + i] = pack2bf(oacc[dt][2 * i], oacc[dt][2 * i + 1]);
    part_l[(size_t)rec * 512 + w * 64 + l] = lsum;
    return;
  }

  // direct path: normalize, transpose O^T[d][q] -> [q][d] through LDS (overlaid), store
  float ltot = lsum + __shfl_xor(lsum, 32);
  float invl = 1.0f / ltot;
  u16* myl = shm + w * 2176;
#pragma unroll
  for (int dt = 0; dt < 2; dt++)
#pragma unroll
    for (int i = 0; i < 8; i++) {
      int d = ((2 * i) & 3) + 8 * (i >> 1) + 4 * h + dt * 32;
      u32 pkv = pack2bf(oacc[dt][2 * i] * invl, oacc[dt][2 * i + 1] * invl);
      *reinterpret_cast<u32*>(myl + lq * 68 + d) = pkv;
    }

  int b = head >> 4, hh = head & 15;
  int gbase = b * 2048 + q0w;
#pragma unroll
  for (int i = 0; i < 8; i++) {
    int chunkk = i * 64 + l;
    int row = chunkk >> 4, col4 = (chunkk & 15) * 4;
    u32x2 v = *reinterpret_cast<const u32x2*>(myl + row * 68 + col4);
    *reinterpret_cast<u32x2*>(Ctx + (gbase + row) * 1024 + hh * 64 + col4) = v;
  }
}

// ---------------- combine 2-4 partials per (head, qc>=4, wave q-tile) -> Ctx --------
// 256 blocks x 256 threads; wave wv handles unit blockIdx*4+wv of 1024.
__global__ __launch_bounds__(256) void attn_combine(const u16* __restrict__ part_o,
                                                    const float* __restrict__ part_l,
                                                    u16* __restrict__ Ctx) {
  __shared__ __align__(16) u16 tl[4][32 * 68];
  int wv = threadIdx.x >> 6, l = threadIdx.x & 63;
  int lq = l & 31, h = l >> 5;
  int unit = blockIdx.x * 4 + wv;  // 1024 = 32 heads x 4 qc x 8 w
  int head = unit & 31, rest = unit >> 5;
  int qc = 4 + (rest >> 3), w = rest & 7;
  int nc = (qc == 4) ? 2 : (qc == 7) ? 4 : 3;
  int base = (qc == 4) ? 0 : (qc == 5) ? 2 : (qc == 6) ? 5 : 8;
  int rec0 = head * 12 + base;

  float lsum = 0.f;
  float of[32];
#pragma unroll
  for (int i = 0; i < 32; i++) of[i] = 0.f;
  for (int cc = 0; cc < nc; cc++) {
    int rec = rec0 + cc;
    lsum += part_l[(size_t)rec * 512 + w * 64 + l];
    const u32* po =
        reinterpret_cast<const u32*>(part_o) + (size_t)rec * 8192 + w * 1024 + l * 16;
#pragma unroll
    for (int uu = 0; uu < 16; uu++) {
      u32 a = po[uu];
      of[2 * uu] += bf2f(a & 0xFFFFu);
      of[2 * uu + 1] += bf2f(a >> 16);
    }
  }

  float ltot = lsum + __shfl_xor(lsum, 32);
  float invl = 1.0f / ltot;

  u16* myl = tl[wv];
#pragma unroll
  for (int dt = 0; dt < 2; dt++)
#pragma unroll
    for (int i = 0; i < 8; i++) {
      int uu = dt * 8 + i;
      int d = ((2 * i) & 3) + 8 * (i >> 1) + 4 * h + dt * 32;
      *reinterpret_cast<u32*>(myl + lq * 68 + d) =
          pack2bf(of[2 * uu] * invl, of[2 * uu + 1] * invl);
    }

  int b_ = head >> 4, hh = head & 15;
  int gbase = b_ * 2048 + qc * 256 + w * 32;
#pragma unroll
  for (int i = 0; i < 8; i++) {
    int chunkk = i * 64 + l;
    int row = chunkk >> 4, col4 = (chunkk & 15) * 4;
    u32x2 v = *reinterpret_cast<const u32x2*>(myl + row * 68 + col4);
    *reinterpret_cast<u32x2*>(Ctx + (gbase + row) * 1024 + hh * 64 + col4) = v;
  }
}

extern "C" void kernel_launch(void* const* d_in, const int* in_sizes, int n_in,
                              void* d_out, int out_size, void* d_ws, size_t ws_size,
                              hipStream_t stream) {
  const float* x = (const float*)d_in[0];
  const float* wq = (const float*)d_in[1];
  const float* wk = (const float*)d_in[2];
  const float* wv = (const float*)d_in[3];
  const float* wo = (const float*)d_in[4];
  const float* bo = (const float*)d_in[5];

  char* ws = (char*)d_ws;
  const size_t MB = 1 << 20;
  u16* xb    = (u16*)(ws + 0 * MB);    // 8 MB : x bf16 (dead after QKV GEMM)
  u16* wqkvt = (u16*)(ws + 8 * MB);    // 6 MB : [wq^T;wk^T;wv^T] (dead after QKV GEMM)
  u16* wot   = (u16*)(ws + 14 * MB);   // 2 MB : wo^T (live until final GEMM)
  u16* qkv   = (u16*)(ws + 16 * MB);   // 24 MB: qb @16, kb @24, vtb @32
  u16* ctx   = (u16*)(ws + 40 * MB);   // 8 MB : ctx [4096][1024]
  // attention partials alias the dead xb/wqkvt region (13.4 MB < 14 MB):
  u16* part_o   = (u16*)(ws + 0 * MB);        // 12 MB : 384 records x 32 KB
  float* part_l = (float*)(ws + 12582912);    // 0.75 MB: 384 records x 512 floats

  const float QSCALE = 0.125f * 1.44269504f;  // 1/sqrt(64) * log2(e)

  cvt_bf16<<<4096, 256, 0, stream>>>(x, xb, 1048576);
  transp4<<<dim3(16, 16, 4), 256, 0, stream>>>(wq, wk, wv, wo, wqkvt, wot, QSCALE);

  gemm2<0><<<dim3(24, 32), 256, 0, stream>>>(xb, wqkvt, nullptr, qkv);

  attn_kernel<<<512, 512, 0, stream>>>(qkv, qkv + 4194304, qkv + 8388608, ctx,
                                       part_o, part_l);
  attn_combine<<<256, 256, 0, stream>>>(part_o, part_l, ctx);

  gemm2<1><<<dim3(8, 32), 256, 0, stream>>>(ctx, wot, bo, d_out);
}